// Round 13
// baseline (3065.962 us; speedup 1.0000x reference)
//
#include <hip/hip_runtime.h>
#include <stdint.h>

// CondDecoder: B=256, T=128, V=64, L=128, H=512, E=32, NL=3, IN0=161
// LAYER-PIPELINED design: one mega-kernel holds all 3 GRU layers resident
// (192 blocks = 3 layers x 16 rowgroups x 4 colblocks). Each block keeps its
// fused [Wih;Whh] slice in registers (K=1024; layer0 x padded 161->512) and
// computes gates directly from the pulled x-tile — no bulk gi GEMMs at all.
// Layers run software-pipelined offset by 1 step: serial depth ~130 rounds
// instead of 384 + GEMMs. h exchange: R12's proven MALL atomic protocol.
#define TT 128

typedef __attribute__((ext_vector_type(8))) short bf16x8;
typedef __attribute__((ext_vector_type(4))) float f32x4;

__device__ __forceinline__ unsigned short f2bf(float f){
  unsigned int x = __builtin_bit_cast(unsigned int, f);
  x = x + 0x7fffu + ((x >> 16) & 1u);
  return (unsigned short)(x >> 16);
}
__device__ __forceinline__ float bf2f(unsigned short u){
  unsigned int x = ((unsigned int)u) << 16;
  return __builtin_bit_cast(float, x);
}

// ---- prep: fused [Wih(pad512) ; Whh] -> fragment-permuted bf16 per layer.
// dst i = (((wblk*3+g)*32+ks)*64+lane)*8+e ; k = ks*32+(lane>>4)*8+e in [0,1024)
__global__ __launch_bounds__(256) void kwf(const float* __restrict__ wih, int kxr,
    const float* __restrict__ whh, unsigned short* __restrict__ dst){
  size_t i = (size_t)blockIdx.x*256 + threadIdx.x;   // grid 6144 -> 1,572,864
  int e = (int)(i & 7), lane = (int)((i >> 3) & 63), ks = (int)((i >> 9) & 31);
  int rem = (int)(i >> 14);                          // wblk*3+g, < 96
  int g = rem % 3, wblk = rem / 3;
  int gr = g*512 + wblk*16 + (lane & 15);
  int k = ks*32 + ((lane >> 4) << 3) + e;
  float v;
  if (k < 512) v = (k < kxr) ? wih[(size_t)gr*kxr + k] : 0.f;
  else         v = whh[(size_t)gr*512 + (k - 512)];
  dst[i] = f2bf(v);
}

// ---- prep: fc_W transpose to [512][64] f32
__global__ __launch_bounds__(256) void kfcw(const float* __restrict__ fcw,
    float* __restrict__ fcwt){
  int i = blockIdx.x*256 + threadIdx.x;   // grid 128 -> 32768
  int k = i >> 6, v = i & 63;
  fcwt[i] = fcw[v*512 + k];
}

// ---- prep: x0 [t*256+b][512] bf16 (latent | shifted-embed | enthalpy | zeros)
__global__ __launch_bounds__(256) void kx0(const float* __restrict__ latent,
    const float* __restrict__ enth, const int* __restrict__ inp,
    const float* __restrict__ emb, unsigned short* __restrict__ x0p){
  int m = blockIdx.x;                     // grid 32768
  int b = m & 255, t = m >> 8;
  for (int c = threadIdx.x; c < 512; c += 256){
    float v = 0.f;
    if (c < 128) v = latent[b*128 + c];
    else if (c < 160){
      int tok = (t == 0) ? 0 : inp[b*128 + t - 1];
      v = emb[tok*32 + (c - 128)];
    }
    else if (c == 160) v = enth[b];
    x0p[(size_t)m*512 + c] = f2bf(v);
  }
}

// ---- mega-kernel: 3 pipelined GRU layers. bid = layer*64 + rg*4... (rg=r&15, cb=r>>4)
__global__ __launch_bounds__(512, 1) void kmega(
    const unsigned short* __restrict__ Wp,     // [3][1,572,864] fused permuted
    const float* __restrict__ bih0, const float* __restrict__ bhh0,
    const float* __restrict__ bih1, const float* __restrict__ bhh1,
    const float* __restrict__ bih2, const float* __restrict__ bhh2,
    const unsigned short* __restrict__ x0p,
    unsigned short* __restrict__ hist0, unsigned short* __restrict__ hist1,
    unsigned short* __restrict__ hist2,
    float* __restrict__ x2f, int* __restrict__ flags){
  const int bid = blockIdx.x;
  const int l = bid >> 6, r = bid & 63;
  const int rg = r & 15, cb = r >> 4;
  const int b0 = rg*16;
  const int tid = threadIdx.x;
  const int w = tid >> 6, lane = tid & 63;
  const int c = lane & 15, lq = lane >> 4;
  const int gcol = cb*128 + w*16 + c;
  __shared__ __align__(16) unsigned short hsX[2][16*512];  // 32KB x-tile dbuf
  __shared__ __align__(16) unsigned short hsH[2][16*512];  // 32KB own-h dbuf
  __shared__ __align__(16) unsigned short hpub[8][256];    // 4KB publish shuffle
  __shared__ __align__(16) float hpf[8][256];              // 8KB f32 (layer 2)

  // resident fused weights: wf[g][ks], ks<16 = x-part, ks>=16 = h-part (96 regs)
  const unsigned short* wbase = Wp + (size_t)l*1572864
      + (size_t)(cb*8 + w)*49152 + lane*8;
  bf16x8 wf[3][32];
  #pragma unroll
  for (int g = 0; g < 3; ++g)
    #pragma unroll
    for (int ks = 0; ks < 32; ++ks)
      wf[g][ks] = *(const bf16x8*)(wbase + g*16384 + ks*512);
  const float* bihp = (l == 0) ? bih0 : ((l == 1) ? bih1 : bih2);
  const float* bhhp = (l == 0) ? bhh0 : ((l == 1) ? bhh1 : bhh2);
  float bi[3], bh[3];
  #pragma unroll
  for (int g = 0; g < 3; ++g){ bi[g] = bihp[g*512 + gcol]; bh[g] = bhhp[g*512 + gcol]; }
  float h_old[4] = {0.f, 0.f, 0.f, 0.f};

  const unsigned short* xsrc = (l == 0) ? x0p : ((l == 1) ? hist0 : hist1);
  unsigned short* hdst = (l == 0) ? hist0 : ((l == 1) ? hist1 : hist2);
  const unsigned long long* xsrc8 = (const unsigned long long*)xsrc;
  unsigned long long* hdst8 = (unsigned long long*)hdst;
  int* fown = flags + l*512 + rg*32;
  const int* fcrs = flags + (l - 1)*512 + rg*32;   // only used when l>0

  #pragma unroll 1
  for (int t = 0; t < TT; ++t){
    unsigned long long pxv[4];
    const unsigned long long* sx = xsrc8 + ((size_t)t*256 + b0)*128;
    if (l == 0){                        // x0 precomputed: plain loads, issued early
      #pragma unroll
      for (int j = 0; j < 4; ++j) pxv[j] = sx[tid + j*512];
    } else if (w == 1){                 // cross-layer poll: h_{l-1}(t) published?
      while (true){
        int f = __hip_atomic_load(fcrs + (lane & 31), __ATOMIC_RELAXED, __HIP_MEMORY_SCOPE_AGENT);
        if (__all(f >= t + 1)) break;
        __builtin_amdgcn_s_sleep(1);
      }
    }
    __syncthreads();                                   // A: x source ready
    if (l > 0){                          // atomic x pull (RTT hides under own-spin)
      #pragma unroll
      for (int j = 0; j < 4; ++j)
        pxv[j] = __hip_atomic_load(sx + tid + j*512, __ATOMIC_RELAXED, __HIP_MEMORY_SCOPE_AGENT);
    }
    if (t > 0 && w == 0){                // own-layer poll: h_l(t-1) published?
      while (true){
        int f = __hip_atomic_load(fown + (lane & 31), __ATOMIC_RELAXED, __HIP_MEMORY_SCOPE_AGENT);
        if (__all(f >= t)) break;
        __builtin_amdgcn_s_sleep(1);
      }
    }
    __syncthreads();                                   // B: own h ready
    if (t > 0){                          // pull own h(t-1) -> swizzled LDS
      const unsigned long long* sh = hdst8 + ((size_t)(t - 1)*256 + b0)*128;
      unsigned long long phv[4];
      #pragma unroll
      for (int j = 0; j < 4; ++j)
        phv[j] = __hip_atomic_load(sh + tid + j*512, __ATOMIC_RELAXED, __HIP_MEMORY_SCOPE_AGENT);
      char* hw = (char*)hsH[t & 1];
      #pragma unroll
      for (int j = 0; j < 4; ++j){
        int idx = tid + j*512;
        int row = idx >> 7, q = idx & 127;
        *(unsigned long long*)(hw + row*1024 + (((q >> 1) ^ (row & 7)) << 4)
                               + ((q & 1) << 3)) = phv[j];
      }
    }
    {                                    // stage x -> swizzled LDS
      char* xw = (char*)hsX[t & 1];
      #pragma unroll
      for (int j = 0; j < 4; ++j){
        int idx = tid + j*512;
        int row = idx >> 7, q = idx & 127;
        *(unsigned long long*)(xw + row*1024 + (((q >> 1) ^ (row & 7)) << 4)
                               + ((q & 1) << 3)) = pxv[j];
      }
    }
    __syncthreads();                                   // C: staging complete
    f32x4 ax[3] = {}; f32x4 ah[3] = {};
    {
      const char* xr = (const char*)hsX[t & 1];
      #pragma unroll
      for (int ks = 0; ks < 16; ++ks){
        bf16x8 af = *(const bf16x8*)(xr + c*1024 + (((ks*4 + lq) ^ (c & 7)) << 4));
        ax[0] = __builtin_amdgcn_mfma_f32_16x16x32_bf16(af, wf[0][ks], ax[0], 0, 0, 0);
        ax[1] = __builtin_amdgcn_mfma_f32_16x16x32_bf16(af, wf[1][ks], ax[1], 0, 0, 0);
        ax[2] = __builtin_amdgcn_mfma_f32_16x16x32_bf16(af, wf[2][ks], ax[2], 0, 0, 0);
      }
    }
    if (t > 0){
      const char* hr = (const char*)hsH[t & 1];
      #pragma unroll
      for (int ks = 0; ks < 16; ++ks){
        bf16x8 af = *(const bf16x8*)(hr + c*1024 + (((ks*4 + lq) ^ (c & 7)) << 4));
        ah[0] = __builtin_amdgcn_mfma_f32_16x16x32_bf16(af, wf[0][16 + ks], ah[0], 0, 0, 0);
        ah[1] = __builtin_amdgcn_mfma_f32_16x16x32_bf16(af, wf[1][16 + ks], ah[1], 0, 0, 0);
        ah[2] = __builtin_amdgcn_mfma_f32_16x16x32_bf16(af, wf[2][16 + ks], ah[2], 0, 0, 0);
      }
    }
    // gates (fully in-lane)
    unsigned short hv[4]; float hf[4];
    #pragma unroll
    for (int q = 0; q < 4; ++q){
      float rr = 1.f/(1.f + __expf(-(ax[0][q] + bi[0] + ah[0][q] + bh[0])));
      float zz = 1.f/(1.f + __expf(-(ax[1][q] + bi[1] + ah[1][q] + bh[1])));
      float np = ax[2][q] + bi[2] + rr*(ah[2][q] + bh[2]);
      float ee = __expf(2.f*np);
      float nn = 1.f - 2.f/(ee + 1.f);
      float hn = (1.f - zz)*nn + zz*h_old[q];
      h_old[q] = hn; hf[q] = hn; hv[q] = f2bf(hn);
    }
    // publish h_t (wave-local shuffle -> 1x8B atomic/lane -> drain -> wave flag)
    #pragma unroll
    for (int q = 0; q < 4; ++q)
      hpub[w][(lq*4 + q)*16 + c] = hv[q];
    if (l == 2){
      #pragma unroll
      for (int q = 0; q < 4; ++q)
        hpf[w][(lq*4 + q)*16 + c] = hf[q];
    }
    __builtin_amdgcn_sched_barrier(0);
    unsigned long long pub = *(const unsigned long long*)&hpub[w][(lane >> 2)*16 + (lane & 3)*4];
    unsigned long long* dst8 = hdst8 + ((size_t)t*256 + b0)*128;
    __hip_atomic_store(dst8 + (lane >> 2)*128 + cb*32 + w*4 + (lane & 3), pub,
                       __ATOMIC_RELAXED, __HIP_MEMORY_SCOPE_AGENT);
    asm volatile("s_waitcnt vmcnt(0)" ::: "memory");   // this wave's h at MALL
    if (lane == 0)
      __hip_atomic_store(fown + (cb*8 + w), t + 1, __ATOMIC_RELAXED, __HIP_MEMORY_SCOPE_AGENT);
    __builtin_amdgcn_sched_barrier(0);                 // x2f strictly after flag
    if (l == 2){
      const float* pf = &hpf[w][(lane >> 2)*16 + (lane & 3)*4];
      unsigned long long f0 = ((const unsigned long long*)pf)[0];
      unsigned long long f1 = ((const unsigned long long*)pf)[1];
      unsigned long long* xd = (unsigned long long*)x2f
          + ((size_t)t*256 + b0 + (lane >> 2))*256 + cb*64 + w*8 + (lane & 3)*2;
      xd[0] = f0; xd[1] = f1;
    }
  }
}

// ---- final FC in f32: logits[b][t][64] = x2f[(t,b)][512] @ fcwt + fc_b
__global__ __launch_bounds__(256) void kfc(const float* __restrict__ x,
    const float* __restrict__ wt, const float* __restrict__ fcb, float* __restrict__ out){
  __shared__ __align__(16) float xs[16*512];
  const int m0 = blockIdx.x*16;   // grid 2048
  for (int c = threadIdx.x; c < 2048; c += 256){
    int row = c >> 7, o = c & 127;
    *(f32x4*)&xs[row*512 + o*4] = *(const f32x4*)(x + (size_t)(m0+row)*512 + o*4);
  }
  __syncthreads();
  const int colv = threadIdx.x & 63, rq = threadIdx.x >> 6;
  float a0 = 0.f, a1 = 0.f, a2 = 0.f, a3 = 0.f;
  const float* x0p = xs + (rq*4 + 0)*512;
  const float* x1p = xs + (rq*4 + 1)*512;
  const float* x2p = xs + (rq*4 + 2)*512;
  const float* x3p = xs + (rq*4 + 3)*512;
  #pragma unroll 8
  for (int k = 0; k < 512; ++k){
    float w = wt[k*64 + colv];
    a0 += w * x0p[k]; a1 += w * x1p[k]; a2 += w * x2p[k]; a3 += w * x3p[k];
  }
  float bv = fcb[colv];
  float av[4] = {a0, a1, a2, a3};
  #pragma unroll
  for (int j = 0; j < 4; ++j){
    int m = m0 + rq*4 + j;
    int b = m & 255, t = m >> 8;               // (t,b) -> [b][t][64]
    out[((size_t)b*128 + t)*64 + colv] = av[j] + bv;
  }
}

extern "C" void kernel_launch(void* const* d_in, const int* in_sizes, int n_in,
                              void* d_out, int out_size, void* d_ws, size_t ws_size,
                              hipStream_t stream){
  const float* latent = (const float*)d_in[0];
  const float* enth   = (const float*)d_in[1];
  const int*   inp    = (const int*)d_in[2];
  const float* emb    = (const float*)d_in[3];
  const float* Wih0   = (const float*)d_in[4];
  const float* Whh0   = (const float*)d_in[5];
  const float* bih0   = (const float*)d_in[6];
  const float* bhh0   = (const float*)d_in[7];
  const float* Wih1   = (const float*)d_in[8];
  const float* Whh1   = (const float*)d_in[9];
  const float* bih1   = (const float*)d_in[10];
  const float* bhh1   = (const float*)d_in[11];
  const float* Wih2   = (const float*)d_in[12];
  const float* Whh2   = (const float*)d_in[13];
  const float* bih2   = (const float*)d_in[14];
  const float* bhh2   = (const float*)d_in[15];
  const float* fcW    = (const float*)d_in[16];
  const float* fcb    = (const float*)d_in[17];

  char* ws = (char*)d_ws;
  constexpr size_t SZH  = (size_t)32768*512*2;                  // 32MB
  constexpr size_t OFF_X0P  = 8192;                             // flags at 0 (8KB)
  constexpr size_t OFF_H0   = OFF_X0P + SZH;
  constexpr size_t OFF_H1   = OFF_H0  + SZH;
  constexpr size_t OFF_H2   = OFF_H1  + SZH;
  constexpr size_t OFF_X2F  = OFF_H2  + SZH;
  constexpr size_t OFF_WP   = OFF_X2F + (size_t)32768*512*4;    // 64MB
  constexpr size_t OFF_FCWT = OFF_WP  + (size_t)3*1572864*2;

  int* flags            = (int*)ws;
  unsigned short* x0p   = (unsigned short*)(ws + OFF_X0P);
  unsigned short* hist0 = (unsigned short*)(ws + OFF_H0);
  unsigned short* hist1 = (unsigned short*)(ws + OFF_H1);
  unsigned short* hist2 = (unsigned short*)(ws + OFF_H2);
  float* x2f            = (float*)(ws + OFF_X2F);
  unsigned short* wp    = (unsigned short*)(ws + OFF_WP);
  float* fcwt           = (float*)(ws + OFF_FCWT);

  kwf<<<6144, 256, 0, stream>>>(Wih0, 161, Whh0, wp);
  kwf<<<6144, 256, 0, stream>>>(Wih1, 512, Whh1, wp + (size_t)1572864);
  kwf<<<6144, 256, 0, stream>>>(Wih2, 512, Whh2, wp + (size_t)2*1572864);
  kfcw<<<128, 256, 0, stream>>>(fcW, fcwt);
  kx0 <<<32768, 256, 0, stream>>>(latent, enth, inp, emb, x0p);
  (void)hipMemsetAsync(flags, 0, 8192, stream);
  kmega<<<192, 512, 0, stream>>>(wp, bih0, bhh0, bih1, bhh1, bih2, bhh2,
                                 x0p, hist0, hist1, hist2, x2f, flags);
  kfc <<<2048, 256, 0, stream>>>(x2f, fcwt, fcb, (float*)d_out);
}

// Round 14
// 1349.991 us; speedup vs baseline: 2.2711x; 2.2711x over previous
//
#include <hip/hip_runtime.h>
#include <stdint.h>

// CondDecoder: B=256, T=128, V=64, L=128, H=512, E=32, NL=3, IN0=161 (pad 192)
// (t,b)-major activations: row m = t*256 + b. hist = h-exchange AND next-GEMM A.
#define TT 128
#define G3 1536

typedef __attribute__((ext_vector_type(8))) short bf16x8;
typedef __attribute__((ext_vector_type(4))) float f32x4;
typedef __attribute__((ext_vector_type(4))) unsigned int u32x4;

__device__ __forceinline__ unsigned short f2bf(float f){
  unsigned int x = __builtin_bit_cast(unsigned int, f);
  x = x + 0x7fffu + ((x >> 16) & 1u);
  return (unsigned short)(x >> 16);
}
__device__ __forceinline__ float bf2f(unsigned short u){
  unsigned int x = ((unsigned int)u) << 16;
  return __builtin_bit_cast(float, x);
}
__device__ __forceinline__ void gl_lds16(const void* g, void* l){
  __builtin_amdgcn_global_load_lds((const __attribute__((address_space(1))) unsigned int*)g,
                                   (__attribute__((address_space(3))) unsigned int*)l, 16, 0, 0);
}

// ---- prep: Wih1, Wih2 f32 -> bf16 flat
__global__ __launch_bounds__(256) void kconv2(const float* __restrict__ a0,
    const float* __restrict__ a1, unsigned short* __restrict__ d0,
    unsigned short* __restrict__ d1){
  int i = blockIdx.x*256 + threadIdx.x;   // grid 3072*256 = 786432
  d0[i] = f2bf(a0[i]); d1[i] = f2bf(a1[i]);
}

// ---- prep: Whh -> fragment-permuted bf16 (wblk = gcol/16 in [0,32))
// dst i = (((wblk*3+g)*16+ks)*64+lane)*8+e
__global__ __launch_bounds__(256) void kwperm(const float* __restrict__ wsrc,
    unsigned short* __restrict__ o){
  int i = blockIdx.x*256 + threadIdx.x;   // grid 3072
  int e = i & 7, lane = (i >> 3) & 63, ks = (i >> 9) & 15, rem = i >> 13;
  int g = rem % 3, wblk = rem / 3;
  int gcol = wblk*16 + (lane & 15);
  int k = ks*32 + (lane >> 4)*8 + e;
  o[i] = f2bf(wsrc[(size_t)(g*512 + gcol)*512 + k]);
}

// ---- prep: Wih0 pad 161->192 to bf16; fc_W transpose to [512][64] f32
__global__ __launch_bounds__(256) void kmisc(const float* __restrict__ wih0,
    unsigned short* __restrict__ wih0p, const float* __restrict__ fcw,
    float* __restrict__ fcwt){
  int i = blockIdx.x*256 + threadIdx.x;  // grid 1152
  if (i < 1536*192){
    int n = i / 192, k = i - n*192;
    wih0p[i] = (k < 161) ? f2bf(wih0[n*161 + k]) : (unsigned short)0;
  }
  if (i < 512*64){
    int k = i >> 6, v = i & 63;
    fcwt[i] = fcw[v*512 + k];
  }
}

// ---- prep: x0 [32768][192] bf16 in (t,b) order
__global__ __launch_bounds__(192) void kx0(const float* __restrict__ latent,
    const float* __restrict__ enth, const int* __restrict__ inp,
    const float* __restrict__ emb, unsigned short* __restrict__ x0){
  int c = threadIdx.x;
  #pragma unroll
  for (int mr = 0; mr < 4; ++mr){
    int m = blockIdx.x*4 + mr;       // grid 8192
    int b = m & 255, t = m >> 8;
    float v;
    if (c < 128) v = latent[b*128 + c];
    else if (c < 160){
      int tok = (t == 0) ? 0 : inp[b*128 + t - 1];
      v = emb[tok*32 + (c - 128)];
    }
    else if (c == 160) v = enth[b];
    else v = 0.f;
    x0[(size_t)m*192 + c] = f2bf(v);
  }
}

// ---- bf16 MFMA GEMM: C[m][n] = A[m][K] @ Bt[n][K]^T + bias[n]; bf16 out
__global__ __launch_bounds__(256) void kgemm(const unsigned short* __restrict__ A,
    const unsigned short* __restrict__ Bt, const float* __restrict__ bias,
    unsigned short* __restrict__ C, int K){
  __shared__ __align__(16) unsigned short As[128*32];
  __shared__ __align__(16) unsigned short Bs[128*32];
  const int m0 = blockIdx.y*128, n0 = blockIdx.x*128;
  const int wv = threadIdx.x >> 6, lane = threadIdx.x & 63;
  const int woffM = (wv >> 1)*64, woffN = (wv & 1)*64;
  f32x4 acc[4][4] = {};
  for (int k0 = 0; k0 < K; k0 += 32){
    __syncthreads();
    #pragma unroll
    for (int i = 0; i < 4; ++i){
      int e = wv*4 + i;
      int ee = e & 7;
      int row = ee*16 + (lane >> 2);
      if (e < 8) gl_lds16(A  + (size_t)(m0+row)*K + k0 + (lane & 3)*8, (void*)&As[ee*512]);
      else       gl_lds16(Bt + (size_t)(n0+row)*K + k0 + (lane & 3)*8, (void*)&Bs[ee*512]);
    }
    __syncthreads();
    bf16x8 af[4], bf_[4];
    #pragma unroll
    for (int mt = 0; mt < 4; ++mt)
      af[mt] = *(const bf16x8*)&As[(woffM + mt*16 + (lane & 15))*32 + (lane >> 4)*8];
    #pragma unroll
    for (int nt = 0; nt < 4; ++nt)
      bf_[nt] = *(const bf16x8*)&Bs[(woffN + nt*16 + (lane & 15))*32 + (lane >> 4)*8];
    #pragma unroll
    for (int mt = 0; mt < 4; ++mt)
      #pragma unroll
      for (int nt = 0; nt < 4; ++nt)
        acc[mt][nt] = __builtin_amdgcn_mfma_f32_16x16x32_bf16(af[mt], bf_[nt], acc[mt][nt], 0, 0, 0);
  }
  const int col = lane & 15, lq = lane >> 4;
  #pragma unroll
  for (int nt = 0; nt < 4; ++nt){
    float bv = bias[n0 + woffN + nt*16 + col];
    #pragma unroll
    for (int mt = 0; mt < 4; ++mt)
      #pragma unroll
      for (int r = 0; r < 4; ++r){
        int grow = m0 + woffM + mt*16 + lq*4 + r;
        int gcol = n0 + woffN + nt*16 + col;
        C[(size_t)grow*G3 + gcol] = f2bf(acc[mt][nt][r] + bv);
      }
  }
}

// ---- GRU layer: 128 blocks = 16 rowgroups(16 rows) x 8 colblocks(64 cols x 3 gates).
// 256 THREADS = 4 waves = 1 wave/SIMD -> full ~512-reg unified budget/wave:
// weights (192 regs/lane) + working (~80) finally FIT — 512-thread blocks'
// 2-wave/SIMD 256-reg ceiling forced reload-from-L2 every step (R10-R13).
// Protocol: flags + publish = atomics (proven); PULLS = PLAIN dwordx4 loads —
// per-t hist slots are read-once-after-flag -> consumer L2 cannot hold a stale
// line (R5 NaN = reused dbuf slots; R9 hang = polled flags via sc0; neither
// pattern applies; kgemm already reads atomic-written hist plainly, correct).
template<int STORE_F>
__global__ __launch_bounds__(256, 1) void kgru(
    const unsigned short* __restrict__ Wp, const float* __restrict__ bhh,
    const unsigned short* __restrict__ gi,
    unsigned short* __restrict__ hist, float* __restrict__ x2f,
    int* __restrict__ flags){
  const int bid = blockIdx.x;
  const int rg = bid & 15, cb = bid >> 4;
  const int b0 = rg*16;
  const int tid = threadIdx.x;
  const int w = tid >> 6, lane = tid & 63;
  const int c = lane & 15, lq = lane >> 4;
  const int gcol = cb*64 + w*16 + c;
  __shared__ __align__(16) unsigned short hs[2][16*512];   // 32KB staging (dbuf)
  __shared__ __align__(16) unsigned short hpub[4][256];    // 2KB publish shuffle
  __shared__ __align__(16) float hpf[4][256];              // 4KB f32 (final layer)

  // resident Whh fragments: wblk = cb*4 + w owns cols wblk*16..+15 (192 regs)
  const unsigned short* wbase = Wp + (size_t)(cb*4 + w)*24576 + lane*8;
  bf16x8 wf[3][16];
  #pragma unroll
  for (int g = 0; g < 3; ++g)
    #pragma unroll
    for (int ks = 0; ks < 16; ++ks)
      wf[g][ks] = *(const bf16x8*)(wbase + g*8192 + ks*512);
  float bias[3];
  #pragma unroll
  for (int g = 0; g < 3; ++g) bias[g] = bhh[g*512 + gcol];
  float h_old[4] = {0.f, 0.f, 0.f, 0.f};

  const u32x4* hist16 = (const u32x4*)hist;
  unsigned long long* hist8 = (unsigned long long*)hist;
  int* myf = flags + rg*32;                      // 32 per-wave slots (cb*4+w)
  const unsigned short* gp = gi + (size_t)(b0 + lq*4)*G3 + gcol;
  const int prow = lane >> 2, qo = lane & 3;

  #pragma unroll 1
  for (int t = 0; t < TT; ++t){
    // A: gi loads RAW (conversion deferred -> latency overlaps poll)
    unsigned short gvr[4][3];
    #pragma unroll
    for (int r = 0; r < 4; ++r){
      const unsigned short* p = gp + (size_t)r*G3;
      gvr[r][0] = p[0]; gvr[r][1] = p[512]; gvr[r][2] = p[1024];
    }
    gp += (size_t)256*G3;
    // B: wave0-only poll (atomic — flags are reused, polled addresses)
    if (t > 0 && w == 0){
      while (true){
        int f = __hip_atomic_load(myf + (lane & 31), __ATOMIC_RELAXED, __HIP_MEMORY_SCOPE_AGENT);
        if (__all(f >= t)) break;
        __builtin_amdgcn_s_sleep(1);
      }
    }
    __syncthreads();                               // h_{t-1} fully published
    if (t > 0){
      // C: PLAIN 16B pulls (read-once per-t slot; clean L2 miss -> MALL)
      const u32x4* src = hist16 + ((size_t)(t - 1)*256 + b0)*64;
      u32x4 pv[4];
      #pragma unroll
      for (int j = 0; j < 4; ++j) pv[j] = src[tid + j*256];
      char* hsw = (char*)hs[t & 1];
      #pragma unroll
      for (int j = 0; j < 4; ++j){
        int idx = tid + j*256;
        int row = idx >> 6, c16 = idx & 63;
        *(u32x4*)(hsw + row*1024 + ((c16 ^ (row & 7)) << 4)) = pv[j];
      }
    }
    __syncthreads();                               // staging complete
    // D: convert gi (loads landed long ago)
    f32x4 acc[3]; f32x4 gin;
    #pragma unroll
    for (int r = 0; r < 4; ++r){
      acc[0][r] = bf2f(gvr[r][0]) + bias[0];
      acc[1][r] = bf2f(gvr[r][1]) + bias[1];
      acc[2][r] = bias[2];
      gin[r]    = bf2f(gvr[r][2]);
    }
    if (t > 0){
      const char* hsr = (const char*)hs[t & 1];
      #pragma unroll
      for (int ks = 0; ks < 16; ++ks){
        bf16x8 af = *(const bf16x8*)(hsr + c*1024 + (((ks*4 + lq) ^ (c & 7)) << 4));
        acc[0] = __builtin_amdgcn_mfma_f32_16x16x32_bf16(af, wf[0][ks], acc[0], 0, 0, 0);
        acc[1] = __builtin_amdgcn_mfma_f32_16x16x32_bf16(af, wf[1][ks], acc[1], 0, 0, 0);
        acc[2] = __builtin_amdgcn_mfma_f32_16x16x32_bf16(af, wf[2][ks], acc[2], 0, 0, 0);
      }
    }
    // E: gates (fully in-lane)
    unsigned short hv[4]; float hf[4];
    #pragma unroll
    for (int r = 0; r < 4; ++r){
      float rr = 1.f/(1.f + __expf(-acc[0][r]));
      float zz = 1.f/(1.f + __expf(-acc[1][r]));
      float np = gin[r] + rr*acc[2][r];
      float ee = __expf(2.f*np);
      float nn = 1.f - 2.f/(ee + 1.f);
      float hn = (1.f - zz)*nn + zz*h_old[r];
      h_old[r] = hn; hf[r] = hn; hv[r] = f2bf(hn);
    }
    // F: wave-local publish shuffle (16 rows x 16 cols per wave)
    #pragma unroll
    for (int r = 0; r < 4; ++r)
      hpub[w][(lq*4 + r)*16 + c] = hv[r];
    if (STORE_F){
      #pragma unroll
      for (int r = 0; r < 4; ++r)
        hpf[w][(lq*4 + r)*16 + c] = hf[r];
    }
    __builtin_amdgcn_sched_barrier(0);
    // G: 1 qword/lane atomic publish; per-wave drain; per-wave flag
    unsigned long long pub = *(const unsigned long long*)&hpub[w][prow*16 + qo*4];
    __hip_atomic_store(hist8 + ((size_t)t*256 + b0 + prow)*128 + cb*16 + w*4 + qo,
                       pub, __ATOMIC_RELAXED, __HIP_MEMORY_SCOPE_AGENT);
    asm volatile("s_waitcnt vmcnt(0)" ::: "memory");   // this wave's h at MALL
    if (lane == 0)
      __hip_atomic_store(myf + (cb*4 + w), t + 1, __ATOMIC_RELAXED, __HIP_MEMORY_SCOPE_AGENT);
    __builtin_amdgcn_sched_barrier(0);             // x2f strictly after flag
    if (STORE_F){
      f32x4 fv = *(const f32x4*)&hpf[w][prow*16 + qo*4];
      *(f32x4*)(x2f + ((size_t)t*256 + b0 + prow)*512 + cb*64 + w*16 + qo*4) = fv;
    }
  }
}

// ---- final FC in f32: logits[b][t][64] = x2f[(t,b)][512] @ fcwt + fc_b
__global__ __launch_bounds__(256) void kfc(const float* __restrict__ x,
    const float* __restrict__ wt, const float* __restrict__ fcb, float* __restrict__ out){
  __shared__ __align__(16) float xs[16*512];
  const int m0 = blockIdx.x*16;   // grid 2048
  for (int c = threadIdx.x; c < 2048; c += 256){
    int row = c >> 7, o = c & 127;
    *(f32x4*)&xs[row*512 + o*4] = *(const f32x4*)(x + (size_t)(m0+row)*512 + o*4);
  }
  __syncthreads();
  const int colv = threadIdx.x & 63, rq = threadIdx.x >> 6;
  float a0 = 0.f, a1 = 0.f, a2 = 0.f, a3 = 0.f;
  const float* x0p = xs + (rq*4 + 0)*512;
  const float* x1p = xs + (rq*4 + 1)*512;
  const float* x2p = xs + (rq*4 + 2)*512;
  const float* x3p = xs + (rq*4 + 3)*512;
  #pragma unroll 8
  for (int k = 0; k < 512; ++k){
    float w = wt[k*64 + colv];
    a0 += w * x0p[k]; a1 += w * x1p[k]; a2 += w * x2p[k]; a3 += w * x3p[k];
  }
  float bv = fcb[colv];
  float av[4] = {a0, a1, a2, a3};
  #pragma unroll
  for (int j = 0; j < 4; ++j){
    int m = m0 + rq*4 + j;
    int b = m & 255, t = m >> 8;               // (t,b) -> [b][t][64]
    out[((size_t)b*128 + t)*64 + colv] = av[j] + bv;
  }
}

extern "C" void kernel_launch(void* const* d_in, const int* in_sizes, int n_in,
                              void* d_out, int out_size, void* d_ws, size_t ws_size,
                              hipStream_t stream){
  const float* latent = (const float*)d_in[0];
  const float* enth   = (const float*)d_in[1];
  const int*   inp    = (const int*)d_in[2];
  const float* emb    = (const float*)d_in[3];
  const float* Wih0   = (const float*)d_in[4];
  const float* Whh0   = (const float*)d_in[5];
  const float* bih0   = (const float*)d_in[6];
  const float* bhh0   = (const float*)d_in[7];
  const float* Wih1   = (const float*)d_in[8];
  const float* Whh1   = (const float*)d_in[9];
  const float* bih1   = (const float*)d_in[10];
  const float* bhh1   = (const float*)d_in[11];
  const float* Wih2   = (const float*)d_in[12];
  const float* Whh2   = (const float*)d_in[13];
  const float* bih2   = (const float*)d_in[14];
  const float* bhh2   = (const float*)d_in[15];
  const float* fcW    = (const float*)d_in[16];
  const float* fcb    = (const float*)d_in[17];

  char* ws = (char*)d_ws;
  constexpr size_t OFF_HIST = 4096;                                  // flags at 0 (2KB)
  constexpr size_t OFF_X0   = OFF_HIST + (size_t)32768*512*2;        // 32MB hist
  constexpr size_t OFF_X2F  = OFF_X0   + (size_t)32768*192*2;
  constexpr size_t OFF_WHP  = OFF_X2F  + (size_t)32768*512*4;
  constexpr size_t OFF_WIH0 = OFF_WHP  + (size_t)3*1536*512*2;
  constexpr size_t OFF_WIH1 = OFF_WIH0 + (size_t)1536*192*2;
  constexpr size_t OFF_WIH2 = OFF_WIH1 + (size_t)1536*512*2;
  constexpr size_t OFF_FCWT = OFF_WIH2 + (size_t)1536*512*2;
  constexpr size_t OFF_GI   = OFF_FCWT + (size_t)512*64*4;

  int* flags            = (int*)ws;
  unsigned short* hist  = (unsigned short*)(ws + OFF_HIST);
  unsigned short* x0    = (unsigned short*)(ws + OFF_X0);
  float* x2f            = (float*)(ws + OFF_X2F);
  unsigned short* whp0  = (unsigned short*)(ws + OFF_WHP);
  unsigned short* whp1  = whp0 + (size_t)1536*512;
  unsigned short* whp2  = whp1 + (size_t)1536*512;
  unsigned short* wih0p = (unsigned short*)(ws + OFF_WIH0);
  unsigned short* wih1b = (unsigned short*)(ws + OFF_WIH1);
  unsigned short* wih2b = (unsigned short*)(ws + OFF_WIH2);
  float* fcwt           = (float*)(ws + OFF_FCWT);
  unsigned short* gi    = (unsigned short*)(ws + OFF_GI);

  kconv2<<<3072, 256, 0, stream>>>(Wih1, Wih2, wih1b, wih2b);
  kwperm<<<3072, 256, 0, stream>>>(Whh0, whp0);
  kwperm<<<3072, 256, 0, stream>>>(Whh1, whp1);
  kwperm<<<3072, 256, 0, stream>>>(Whh2, whp2);
  kmisc <<<1152, 256, 0, stream>>>(Wih0, wih0p, fcW, fcwt);
  kx0   <<<8192, 192, 0, stream>>>(latent, enth, inp, emb, x0);

  kgemm<<<dim3(12,256), 256, 0, stream>>>(x0, wih0p, bih0, gi, 192);
  (void)hipMemsetAsync(flags, 0, 2048, stream);
  kgru<0><<<128, 256, 0, stream>>>(whp0, bhh0, gi, hist, x2f, flags);
  kgemm<<<dim3(12,256), 256, 0, stream>>>(hist, wih1b, bih1, gi, 512);
  (void)hipMemsetAsync(flags, 0, 2048, stream);
  kgru<0><<<128, 256, 0, stream>>>(whp1, bhh1, gi, hist, x2f, flags);
  kgemm<<<dim3(12,256), 256, 0, stream>>>(hist, wih2b, bih2, gi, 512);
  (void)hipMemsetAsync(flags, 0, 2048, stream);
  kgru<1><<<128, 256, 0, stream>>>(whp2, bhh2, gi, hist, x2f, flags);
  kfc  <<<2048, 256, 0, stream>>>(x2f, fcwt, fcb, (float*)d_out);
}

// Round 15
// 1345.796 us; speedup vs baseline: 2.2782x; 1.0031x over previous
//
#include <hip/hip_runtime.h>
#include <stdint.h>

// CondDecoder: B=256, T=128, V=64, L=128, H=512, E=32, NL=3, IN0=161 (pad 192)
// (t,b)-major activations: row m = t*256 + b. hist = h-exchange AND next-GEMM A.
#define TT 128
#define G3 1536

typedef __attribute__((ext_vector_type(8))) short bf16x8;
typedef __attribute__((ext_vector_type(4))) float f32x4;
typedef __attribute__((ext_vector_type(4))) unsigned int u32x4;

__device__ __forceinline__ unsigned short f2bf(float f){
  unsigned int x = __builtin_bit_cast(unsigned int, f);
  x = x + 0x7fffu + ((x >> 16) & 1u);
  return (unsigned short)(x >> 16);
}
__device__ __forceinline__ float bf2f(unsigned short u){
  unsigned int x = ((unsigned int)u) << 16;
  return __builtin_bit_cast(float, x);
}
__device__ __forceinline__ void gl_lds16(const void* g, void* l){
  __builtin_amdgcn_global_load_lds((const __attribute__((address_space(1))) unsigned int*)g,
                                   (__attribute__((address_space(3))) unsigned int*)l, 16, 0, 0);
}

// ---- fused prep: Wih1/2 conv + 3x Whh fragment-permute + Wih0 pad + fcW^T + flag zero
__global__ __launch_bounds__(256) void kprep(
    const float* __restrict__ Wih1f, const float* __restrict__ Wih2f,
    unsigned short* __restrict__ wih1b, unsigned short* __restrict__ wih2b,
    const float* __restrict__ Whh0f, const float* __restrict__ Whh1f,
    const float* __restrict__ Whh2f,
    unsigned short* __restrict__ whp0, unsigned short* __restrict__ whp1,
    unsigned short* __restrict__ whp2,
    const float* __restrict__ Wih0f, unsigned short* __restrict__ wih0p,
    const float* __restrict__ fcw, float* __restrict__ fcwt,
    int* __restrict__ flags){
  int bx = blockIdx.x, tid = threadIdx.x;     // grid 13441
  if (bx < 3072){
    int i = bx*256 + tid;                     // Wih1/2 -> bf16 flat
    wih1b[i] = f2bf(Wih1f[i]); wih2b[i] = f2bf(Wih2f[i]);
  } else if (bx < 12288){
    int j = bx - 3072;                        // Whh -> fragment-permuted bf16
    int layer = j / 3072;                     // dst i = (((wblk*3+g)*16+ks)*64+lane)*8+e
    int i = (j - layer*3072)*256 + tid;
    const float* src = (layer == 0) ? Whh0f : ((layer == 1) ? Whh1f : Whh2f);
    unsigned short* dst = (layer == 0) ? whp0 : ((layer == 1) ? whp1 : whp2);
    int e = i & 7, lane = (i >> 3) & 63, ks = (i >> 9) & 15, rem = i >> 13;
    int g = rem % 3, wblk = rem / 3;
    int gcol = wblk*16 + (lane & 15);
    int k = ks*32 + (lane >> 4)*8 + e;
    dst[i] = f2bf(src[(size_t)(g*512 + gcol)*512 + k]);
  } else if (bx < 13440){
    int i = (bx - 12288)*256 + tid;           // Wih0 pad 161->192; fcW transpose
    if (i < 1536*192){
      int n = i / 192, k = i - n*192;
      wih0p[i] = (k < 161) ? f2bf(Wih0f[n*161 + k]) : (unsigned short)0;
    }
    if (i < 512*64){
      int k = i >> 6, v = i & 63;
      fcwt[i] = fcw[v*512 + k];
    }
  } else {
    for (int k = tid; k < 1536; k += 256) flags[k] = 0;   // 3 per-layer flag regions
  }
}

// ---- prep: x0 [32768][192] bf16 in (t,b) order
__global__ __launch_bounds__(192) void kx0(const float* __restrict__ latent,
    const float* __restrict__ enth, const int* __restrict__ inp,
    const float* __restrict__ emb, unsigned short* __restrict__ x0){
  int c = threadIdx.x;
  #pragma unroll
  for (int mr = 0; mr < 4; ++mr){
    int m = blockIdx.x*4 + mr;       // grid 8192
    int b = m & 255, t = m >> 8;
    float v;
    if (c < 128) v = latent[b*128 + c];
    else if (c < 160){
      int tok = (t == 0) ? 0 : inp[b*128 + t - 1];
      v = emb[tok*32 + (c - 128)];
    }
    else if (c == 160) v = enth[b];
    else v = 0.f;
    x0[(size_t)m*192 + c] = f2bf(v);
  }
}

// ---- bf16 MFMA GEMM: C[m][n] = A[m][K] @ Bt[n][K]^T + bias[n]; bf16 out
__global__ __launch_bounds__(256) void kgemm(const unsigned short* __restrict__ A,
    const unsigned short* __restrict__ Bt, const float* __restrict__ bias,
    unsigned short* __restrict__ C, int K){
  __shared__ __align__(16) unsigned short As[128*32];
  __shared__ __align__(16) unsigned short Bs[128*32];
  const int m0 = blockIdx.y*128, n0 = blockIdx.x*128;
  const int wv = threadIdx.x >> 6, lane = threadIdx.x & 63;
  const int woffM = (wv >> 1)*64, woffN = (wv & 1)*64;
  f32x4 acc[4][4] = {};
  for (int k0 = 0; k0 < K; k0 += 32){
    __syncthreads();
    #pragma unroll
    for (int i = 0; i < 4; ++i){
      int e = wv*4 + i;
      int ee = e & 7;
      int row = ee*16 + (lane >> 2);
      if (e < 8) gl_lds16(A  + (size_t)(m0+row)*K + k0 + (lane & 3)*8, (void*)&As[ee*512]);
      else       gl_lds16(Bt + (size_t)(n0+row)*K + k0 + (lane & 3)*8, (void*)&Bs[ee*512]);
    }
    __syncthreads();
    bf16x8 af[4], bf_[4];
    #pragma unroll
    for (int mt = 0; mt < 4; ++mt)
      af[mt] = *(const bf16x8*)&As[(woffM + mt*16 + (lane & 15))*32 + (lane >> 4)*8];
    #pragma unroll
    for (int nt = 0; nt < 4; ++nt)
      bf_[nt] = *(const bf16x8*)&Bs[(woffN + nt*16 + (lane & 15))*32 + (lane >> 4)*8];
    #pragma unroll
    for (int mt = 0; mt < 4; ++mt)
      #pragma unroll
      for (int nt = 0; nt < 4; ++nt)
        acc[mt][nt] = __builtin_amdgcn_mfma_f32_16x16x32_bf16(af[mt], bf_[nt], acc[mt][nt], 0, 0, 0);
  }
  const int col = lane & 15, lq = lane >> 4;
  #pragma unroll
  for (int nt = 0; nt < 4; ++nt){
    float bv = bias[n0 + woffN + nt*16 + col];
    #pragma unroll
    for (int mt = 0; mt < 4; ++mt)
      #pragma unroll
      for (int r = 0; r < 4; ++r){
        int grow = m0 + woffM + mt*16 + lq*4 + r;
        int gcol = n0 + woffN + nt*16 + col;
        C[(size_t)grow*G3 + gcol] = f2bf(acc[mt][nt][r] + bv);
      }
  }
}

// ---- GRU layer: 128 blocks = 16 rowgroups(16 rows) x 8 colblocks(64 cols x 3 gates).
// 256 threads = 4 waves; amdgpu_waves_per_eu(1,1) forces exactly 1 wave/SIMD so the
// allocator may use the full ~512-reg budget: goal is TRUE weight residency (R14's
// VGPR_Count=144 showed Whh was still L2-streamed each step — cheap only because one
// layer's 1.5MB fits XCD L2). Protocol (proven R10-R14): atomic publish + per-wave
// flags + vmcnt drain; PLAIN read-once pulls after flag detect; wave0-only poll.
template<int STORE_F>
__global__ __attribute__((amdgpu_waves_per_eu(1, 1)))
__launch_bounds__(256, 1) void kgru(
    const unsigned short* __restrict__ Wp, const float* __restrict__ bhh,
    const unsigned short* __restrict__ gi,
    unsigned short* __restrict__ hist, float* __restrict__ x2f,
    int* __restrict__ flags){
  const int bid = blockIdx.x;
  const int rg = bid & 15, cb = bid >> 4;
  const int b0 = rg*16;
  const int tid = threadIdx.x;
  const int w = tid >> 6, lane = tid & 63;
  const int c = lane & 15, lq = lane >> 4;
  const int gcol = cb*64 + w*16 + c;
  __shared__ __align__(16) unsigned short hs[2][16*512];   // 32KB staging (dbuf)
  __shared__ __align__(16) unsigned short hpub[4][256];    // 2KB publish shuffle
  __shared__ __align__(16) float hpf[4][256];              // 4KB f32 (final layer)

  // resident Whh fragments: wblk = cb*4 + w owns cols wblk*16..+15 (192 regs)
  const unsigned short* wbase = Wp + (size_t)(cb*4 + w)*24576 + lane*8;
  bf16x8 wf[3][16];
  #pragma unroll
  for (int g = 0; g < 3; ++g)
    #pragma unroll
    for (int ks = 0; ks < 16; ++ks)
      wf[g][ks] = *(const bf16x8*)(wbase + g*8192 + ks*512);
  float bias[3];
  #pragma unroll
  for (int g = 0; g < 3; ++g) bias[g] = bhh[g*512 + gcol];
  float h_old[4] = {0.f, 0.f, 0.f, 0.f};

  const u32x4* hist16 = (const u32x4*)hist;
  unsigned long long* hist8 = (unsigned long long*)hist;
  int* myf = flags + rg*32;                      // 32 per-wave slots (cb*4+w)
  const unsigned short* gp = gi + (size_t)(b0 + lq*4)*G3 + gcol;
  const int prow = lane >> 2, qo = lane & 3;

  #pragma unroll 1
  for (int t = 0; t < TT; ++t){
    // A: gi loads RAW (conversion deferred -> latency overlaps poll)
    unsigned short gvr[4][3];
    #pragma unroll
    for (int r = 0; r < 4; ++r){
      const unsigned short* p = gp + (size_t)r*G3;
      gvr[r][0] = p[0]; gvr[r][1] = p[512]; gvr[r][2] = p[1024];
    }
    gp += (size_t)256*G3;
    // B: wave0-only poll (atomic — flags are reused, polled addresses)
    if (t > 0 && w == 0){
      while (true){
        int f = __hip_atomic_load(myf + (lane & 31), __ATOMIC_RELAXED, __HIP_MEMORY_SCOPE_AGENT);
        if (__all(f >= t)) break;
        __builtin_amdgcn_s_sleep(1);
      }
    }
    __syncthreads();                               // h_{t-1} fully published
    if (t > 0){
      // C: PLAIN 16B pulls (read-once per-t slot; clean L2 miss -> MALL)
      const u32x4* src = hist16 + ((size_t)(t - 1)*256 + b0)*64;
      u32x4 pv[4];
      #pragma unroll
      for (int j = 0; j < 4; ++j) pv[j] = src[tid + j*256];
      char* hsw = (char*)hs[t & 1];
      #pragma unroll
      for (int j = 0; j < 4; ++j){
        int idx = tid + j*256;
        int row = idx >> 6, c16 = idx & 63;
        *(u32x4*)(hsw + row*1024 + ((c16 ^ (row & 7)) << 4)) = pv[j];
      }
    }
    __syncthreads();                               // staging complete
    // D: convert gi (loads landed long ago)
    f32x4 acc[3]; f32x4 gin;
    #pragma unroll
    for (int r = 0; r < 4; ++r){
      acc[0][r] = bf2f(gvr[r][0]) + bias[0];
      acc[1][r] = bf2f(gvr[r][1]) + bias[1];
      acc[2][r] = bias[2];
      gin[r]    = bf2f(gvr[r][2]);
    }
    if (t > 0){
      const char* hsr = (const char*)hs[t & 1];
      #pragma unroll
      for (int ks = 0; ks < 16; ++ks){
        bf16x8 af = *(const bf16x8*)(hsr + c*1024 + (((ks*4 + lq) ^ (c & 7)) << 4));
        acc[0] = __builtin_amdgcn_mfma_f32_16x16x32_bf16(af, wf[0][ks], acc[0], 0, 0, 0);
        acc[1] = __builtin_amdgcn_mfma_f32_16x16x32_bf16(af, wf[1][ks], acc[1], 0, 0, 0);
        acc[2] = __builtin_amdgcn_mfma_f32_16x16x32_bf16(af, wf[2][ks], acc[2], 0, 0, 0);
      }
    }
    // E: gates (fully in-lane)
    unsigned short hv[4]; float hf[4];
    #pragma unroll
    for (int r = 0; r < 4; ++r){
      float rr = 1.f/(1.f + __expf(-acc[0][r]));
      float zz = 1.f/(1.f + __expf(-acc[1][r]));
      float np = gin[r] + rr*acc[2][r];
      float ee = __expf(2.f*np);
      float nn = 1.f - 2.f/(ee + 1.f);
      float hn = (1.f - zz)*nn + zz*h_old[r];
      h_old[r] = hn; hf[r] = hn; hv[r] = f2bf(hn);
    }
    // F: wave-local publish shuffle (16 rows x 16 cols per wave)
    #pragma unroll
    for (int r = 0; r < 4; ++r)
      hpub[w][(lq*4 + r)*16 + c] = hv[r];
    if (STORE_F){
      #pragma unroll
      for (int r = 0; r < 4; ++r)
        hpf[w][(lq*4 + r)*16 + c] = hf[r];
    }
    __builtin_amdgcn_sched_barrier(0);
    // G: 1 qword/lane atomic publish; per-wave drain; per-wave flag
    unsigned long long pub = *(const unsigned long long*)&hpub[w][prow*16 + qo*4];
    __hip_atomic_store(hist8 + ((size_t)t*256 + b0 + prow)*128 + cb*16 + w*4 + qo,
                       pub, __ATOMIC_RELAXED, __HIP_MEMORY_SCOPE_AGENT);
    asm volatile("s_waitcnt vmcnt(0)" ::: "memory");   // this wave's h at MALL
    if (lane == 0)
      __hip_atomic_store(myf + (cb*4 + w), t + 1, __ATOMIC_RELAXED, __HIP_MEMORY_SCOPE_AGENT);
    __builtin_amdgcn_sched_barrier(0);             // x2f strictly after flag
    if (STORE_F){
      f32x4 fv = *(const f32x4*)&hpf[w][prow*16 + qo*4];
      *(f32x4*)(x2f + ((size_t)t*256 + b0 + prow)*512 + cb*64 + w*16 + qo*4) = fv;
    }
  }
}

// ---- final FC in f32: logits[b][t][64] = x2f[(t,b)][512] @ fcwt + fc_b
__global__ __launch_bounds__(256) void kfc(const float* __restrict__ x,
    const float* __restrict__ wt, const float* __restrict__ fcb, float* __restrict__ out){
  __shared__ __align__(16) float xs[16*512];
  const int m0 = blockIdx.x*16;   // grid 2048
  for (int c = threadIdx.x; c < 2048; c += 256){
    int row = c >> 7, o = c & 127;
    *(f32x4*)&xs[row*512 + o*4] = *(const f32x4*)(x + (size_t)(m0+row)*512 + o*4);
  }
  __syncthreads();
  const int colv = threadIdx.x & 63, rq = threadIdx.x >> 6;
  float a0 = 0.f, a1 = 0.f, a2 = 0.f, a3 = 0.f;
  const float* x0p = xs + (rq*4 + 0)*512;
  const float* x1p = xs + (rq*4 + 1)*512;
  const float* x2p = xs + (rq*4 + 2)*512;
  const float* x3p = xs + (rq*4 + 3)*512;
  #pragma unroll 8
  for (int k = 0; k < 512; ++k){
    float w = wt[k*64 + colv];
    a0 += w * x0p[k]; a1 += w * x1p[k]; a2 += w * x2p[k]; a3 += w * x3p[k];
  }
  float bv = fcb[colv];
  float av[4] = {a0, a1, a2, a3};
  #pragma unroll
  for (int j = 0; j < 4; ++j){
    int m = m0 + rq*4 + j;
    int b = m & 255, t = m >> 8;               // (t,b) -> [b][t][64]
    out[((size_t)b*128 + t)*64 + colv] = av[j] + bv;
  }
}

extern "C" void kernel_launch(void* const* d_in, const int* in_sizes, int n_in,
                              void* d_out, int out_size, void* d_ws, size_t ws_size,
                              hipStream_t stream){
  const float* latent = (const float*)d_in[0];
  const float* enth   = (const float*)d_in[1];
  const int*   inp    = (const int*)d_in[2];
  const float* emb    = (const float*)d_in[3];
  const float* Wih0   = (const float*)d_in[4];
  const float* Whh0   = (const float*)d_in[5];
  const float* bih0   = (const float*)d_in[6];
  const float* bhh0   = (const float*)d_in[7];
  const float* Wih1   = (const float*)d_in[8];
  const float* Whh1   = (const float*)d_in[9];
  const float* bih1   = (const float*)d_in[10];
  const float* bhh1   = (const float*)d_in[11];
  const float* Wih2   = (const float*)d_in[12];
  const float* Whh2   = (const float*)d_in[13];
  const float* bih2   = (const float*)d_in[14];
  const float* bhh2   = (const float*)d_in[15];
  const float* fcW    = (const float*)d_in[16];
  const float* fcb    = (const float*)d_in[17];

  char* ws = (char*)d_ws;
  constexpr size_t OFF_HIST = 8192;                                  // flags at 0 (6KB)
  constexpr size_t OFF_X0   = OFF_HIST + (size_t)32768*512*2;        // 32MB hist
  constexpr size_t OFF_X2F  = OFF_X0   + (size_t)32768*192*2;
  constexpr size_t OFF_WHP  = OFF_X2F  + (size_t)32768*512*4;
  constexpr size_t OFF_WIH0 = OFF_WHP  + (size_t)3*1536*512*2;
  constexpr size_t OFF_WIH1 = OFF_WIH0 + (size_t)1536*192*2;
  constexpr size_t OFF_WIH2 = OFF_WIH1 + (size_t)1536*512*2;
  constexpr size_t OFF_FCWT = OFF_WIH2 + (size_t)1536*512*2;
  constexpr size_t OFF_GI   = OFF_FCWT + (size_t)512*64*4;

  int* flags            = (int*)ws;
  unsigned short* hist  = (unsigned short*)(ws + OFF_HIST);
  unsigned short* x0    = (unsigned short*)(ws + OFF_X0);
  float* x2f            = (float*)(ws + OFF_X2F);
  unsigned short* whp0  = (unsigned short*)(ws + OFF_WHP);
  unsigned short* whp1  = whp0 + (size_t)1536*512;
  unsigned short* whp2  = whp1 + (size_t)1536*512;
  unsigned short* wih0p = (unsigned short*)(ws + OFF_WIH0);
  unsigned short* wih1b = (unsigned short*)(ws + OFF_WIH1);
  unsigned short* wih2b = (unsigned short*)(ws + OFF_WIH2);
  float* fcwt           = (float*)(ws + OFF_FCWT);
  unsigned short* gi    = (unsigned short*)(ws + OFF_GI);

  kprep<<<13441, 256, 0, stream>>>(Wih1, Wih2, wih1b, wih2b,
                                   Whh0, Whh1, Whh2, whp0, whp1, whp2,
                                   Wih0, wih0p, fcW, fcwt, flags);
  kx0  <<<8192, 192, 0, stream>>>(latent, enth, inp, emb, x0);

  kgemm<<<dim3(12,256), 256, 0, stream>>>(x0, wih0p, bih0, gi, 192);
  kgru<0><<<128, 256, 0, stream>>>(whp0, bhh0, gi, hist, x2f, flags);
  kgemm<<<dim3(12,256), 256, 0, stream>>>(hist, wih1b, bih1, gi, 512);
  kgru<0><<<128, 256, 0, stream>>>(whp1, bhh1, gi, hist, x2f, flags + 512);
  kgemm<<<dim3(12,256), 256, 0, stream>>>(hist, wih2b, bih2, gi, 512);
  kgru<1><<<128, 256, 0, stream>>>(whp2, bhh2, gi, hist, x2f, flags + 1024);
  kfc  <<<2048, 256, 0, stream>>>(x2f, fcwt, fcb, (float*)d_out);
}